// Round 1
// baseline (408.878 us; speedup 1.0000x reference)
//
#include <hip/hip_runtime.h>
#include <math.h>

#define NB 4
#define NL 2048
#define NH 8
#define ND 64
#define NUPART 80
#define NUTOP 40

// ---------------------------------------------------------------------------
// Kernel 1: M[b,h,l] = max_s(q.k_s) - sum_s(q.k_s)/L over 80 sampled keys.
// One wave per (b,h,l). Lane = s_local(16) x d_group(4); each lane does a
// 16-wide partial dot (4 float4), 2-shuffle reduce within the d-group,
// then a 4-step cross-group reduce at the end.
// ---------------------------------------------------------------------------
__global__ __launch_bounds__(256) void k_compute_M(
    const float* __restrict__ q, const float* __restrict__ k,
    const int* __restrict__ idx, float* __restrict__ M)
{
    const int w    = blockIdx.x * 4 + (threadIdx.x >> 6);   // (b*H+h)*L + l
    const int lane = threadIdx.x & 63;
    const int l    = w & (NL - 1);
    const int bh   = w >> 11;
    const int h    = bh & (NH - 1);
    const int b    = bh >> 3;
    const int sl   = lane >> 2;   // 0..15 sample slot
    const int dg   = lane & 3;    // 0..3 d-group
    const int d0   = dg * 16;

    const float4* qv = (const float4*)(q + (((size_t)(b * NL + l) * NH + h) * ND + d0));
    const float4 q0 = qv[0], q1 = qv[1], q2 = qv[2], q3 = qv[3];

    float mx = -INFINITY, sm = 0.0f;
#pragma unroll
    for (int r = 0; r < 5; ++r) {
        const int s  = r * 16 + sl;
        const int ki = idx[l * NUPART + s];
        const float4* kv = (const float4*)(k + (((size_t)(b * NL + ki) * NH + h) * ND + d0));
        const float4 k0 = kv[0], k1 = kv[1], k2 = kv[2], k3 = kv[3];
        float p = q0.x * k0.x + q0.y * k0.y + q0.z * k0.z + q0.w * k0.w
                + q1.x * k1.x + q1.y * k1.y + q1.z * k1.z + q1.w * k1.w
                + q2.x * k2.x + q2.y * k2.y + q2.z * k2.z + q2.w * k2.w
                + q3.x * k3.x + q3.y * k3.y + q3.z * k3.z + q3.w * k3.w;
        p += __shfl_xor(p, 1);
        p += __shfl_xor(p, 2);
        // all 4 lanes of the d-group now hold the full dot for sample s
        mx = fmaxf(mx, p);
        sm += p;
    }
    // combine the 16 sample-slots (masks 4..32 only: d-group lanes are dups)
#pragma unroll
    for (int m = 4; m < 64; m <<= 1) {
        mx = fmaxf(mx, __shfl_xor(mx, m));
        sm += __shfl_xor(sm, m);
    }
    if (lane == 0) M[w] = mx - sm * (1.0f / (float)NL);
}

// ---------------------------------------------------------------------------
// Kernel 2: per (b,h), top-40 of 2048 M values (iterative argmax,
// lower index wins ties -- matches jax.lax.top_k selection set).
// ---------------------------------------------------------------------------
__global__ __launch_bounds__(256) void k_topk(
    const float* __restrict__ M, int* __restrict__ Mtop)
{
    __shared__ float sM[NL];
    __shared__ float rv[4];
    __shared__ int   ri[4];
    const int bh = blockIdx.x;
    const int t  = threadIdx.x;

    for (int j = t; j < NL; j += 256) sM[j] = M[bh * NL + j];
    __syncthreads();

    for (int it = 0; it < NUTOP; ++it) {
        float v = -INFINITY;
        int   i = NL;
        for (int j = t; j < NL; j += 256) {
            const float m = sM[j];
            if (m > v || (m == v && j < i)) { v = m; i = j; }
        }
#pragma unroll
        for (int off = 1; off < 64; off <<= 1) {
            const float ov = __shfl_xor(v, off);
            const int   oi = __shfl_xor(i, off);
            if (ov > v || (ov == v && oi < i)) { v = ov; i = oi; }
        }
        const int wid = t >> 6;
        if ((t & 63) == 0) { rv[wid] = v; ri[wid] = i; }
        __syncthreads();
        if (t == 0) {
            for (int w2 = 1; w2 < 4; ++w2) {
                if (rv[w2] > v || (rv[w2] == v && ri[w2] < i)) { v = rv[w2]; i = ri[w2]; }
            }
            Mtop[bh * NUTOP + it] = i;
            sM[i] = -INFINITY;
        }
        __syncthreads();
    }
}

// ---------------------------------------------------------------------------
// Kernel 3: for each selected row: scores = (q_row . K^T)/8, softmax,
// write the 2048-wide attn row into the (zeroed) dense output.
// One block (256 thr) per (b,h,u); each thread owns 8 columns.
// ---------------------------------------------------------------------------
__global__ __launch_bounds__(256) void k_attn(
    const float* __restrict__ q, const float* __restrict__ k,
    const int* __restrict__ Mtop, float* __restrict__ out)
{
    __shared__ float redm[4];
    __shared__ float reds[4];

    const int bh  = blockIdx.x / NUTOP;
    const int ui  = blockIdx.x % NUTOP;
    const int b   = bh >> 3;
    const int h   = bh & 7;
    const int row = Mtop[bh * NUTOP + ui];
    const int t   = threadIdx.x;
    const int lane = t & 63;
    const int wid  = t >> 6;

    // q row is wave-uniform: broadcast loads, kept in registers
    const float4* qv = (const float4*)(q + (((size_t)(b * NL + row)) * NH + h) * ND);
    float4 qr[16];
#pragma unroll
    for (int i = 0; i < 16; ++i) qr[i] = qv[i];

    float sc[8];
    float mx = -INFINITY;
#pragma unroll
    for (int j = 0; j < 8; ++j) {
        const int l = t + 256 * j;
        const float4* kv = (const float4*)(k + (((size_t)(b * NL + l)) * NH + h) * ND);
        float s = 0.0f;
#pragma unroll
        for (int i = 0; i < 16; ++i) {
            const float4 kk = kv[i];
            s += qr[i].x * kk.x + qr[i].y * kk.y + qr[i].z * kk.z + qr[i].w * kk.w;
        }
        sc[j] = s * 0.125f;   // 1/sqrt(64)
        mx = fmaxf(mx, sc[j]);
    }

    // block max
#pragma unroll
    for (int off = 1; off < 64; off <<= 1) mx = fmaxf(mx, __shfl_xor(mx, off));
    if (lane == 0) redm[wid] = mx;
    __syncthreads();
    mx = fmaxf(fmaxf(redm[0], redm[1]), fmaxf(redm[2], redm[3]));

    float lsum = 0.0f;
#pragma unroll
    for (int j = 0; j < 8; ++j) {
        sc[j] = __expf(sc[j] - mx);
        lsum += sc[j];
    }
#pragma unroll
    for (int off = 1; off < 64; off <<= 1) lsum += __shfl_xor(lsum, off);
    if (lane == 0) reds[wid] = lsum;
    __syncthreads();
    const float inv = 1.0f / (reds[0] + reds[1] + reds[2] + reds[3]);

    float* orow = out + ((size_t)bh * NL + row) * NL;
#pragma unroll
    for (int j = 0; j < 8; ++j) {
        orow[t + 256 * j] = sc[j] * inv;
    }
}

extern "C" void kernel_launch(void* const* d_in, const int* in_sizes, int n_in,
                              void* d_out, int out_size, void* d_ws, size_t ws_size,
                              hipStream_t stream) {
    const float* q   = (const float*)d_in[0];
    const float* k   = (const float*)d_in[1];
    const int*   idx = (const int*)d_in[2];
    float* out = (float*)d_out;

    float* Mws  = (float*)d_ws;                                   // B*H*L floats
    int*   Mtop = (int*)((char*)d_ws + (size_t)NB * NH * NL * 4); // B*H*40 ints

    // zero the dense output (mostly-zero result)
    hipMemsetAsync(out, 0, (size_t)out_size * sizeof(float), stream);

    k_compute_M<<<NB * NH * NL / 4, 256, 0, stream>>>(q, k, idx, Mws);
    k_topk<<<NB * NH, 256, 0, stream>>>(Mws, Mtop);
    k_attn<<<NB * NH * NUTOP, 256, 0, stream>>>(q, k, Mtop, out);
}

// Round 2
// 385.768 us; speedup vs baseline: 1.0599x; 1.0599x over previous
//
#include <hip/hip_runtime.h>
#include <math.h>

#define NB 4
#define NL 2048
#define NH 8
#define ND 64
#define NUPART 80
#define NUTOP 40

// ---------------------------------------------------------------------------
// Kernel 1 (fused): M[b,h,l] = max_s(q.k_s) - sum_s(q.k_s)/L over 80 sampled
// keys, PLUS zero-fill of a 32 KiB slice of the dense output per block.
// The zero stores (pure BW) hide under the gather latency (pure latency),
// replacing the 320 us rocclr memset (1.7 TB/s) with ~free bandwidth use.
// One wave per (b,h,l); lane = s_local(16) x d_group(4).
// ---------------------------------------------------------------------------
__global__ __launch_bounds__(256) void k_compute_M_zero(
    const float* __restrict__ q, const float* __restrict__ k,
    const int* __restrict__ idx, float* __restrict__ M,
    float4* __restrict__ outz)
{
    const int t    = threadIdx.x;
    const int w    = blockIdx.x * 4 + (t >> 6);   // (b*H+h)*L + l
    const int lane = t & 63;
    const int l    = w & (NL - 1);
    const int bh   = w >> 11;
    const int h    = bh & (NH - 1);
    const int b    = bh >> 3;
    const int sl   = lane >> 2;   // 0..15 sample slot
    const int dg   = lane & 3;    // 0..3 d-group
    const int d0   = dg * 16;

    // ---- zero-fill slice: block i owns out bytes [i*32KiB, (i+1)*32KiB) ----
    // 16384 blocks x 32 KiB = 512 MiB exactly. 8 float4 stores per thread.
    {
        float4* o = outz + (size_t)blockIdx.x * 2048 + t;
        const float4 z = make_float4(0.f, 0.f, 0.f, 0.f);
#pragma unroll
        for (int j = 0; j < 8; ++j) o[j * 256] = z;
    }

    // ---- M computation ----
    const float4* qv = (const float4*)(q + (((size_t)(b * NL + l) * NH + h) * ND + d0));
    const float4 q0 = qv[0], q1 = qv[1], q2 = qv[2], q3 = qv[3];

    float mx = -INFINITY, sm = 0.0f;
#pragma unroll
    for (int r = 0; r < 5; ++r) {
        const int s  = r * 16 + sl;
        const int ki = idx[l * NUPART + s];
        const float4* kv = (const float4*)(k + (((size_t)(b * NL + ki) * NH + h) * ND + d0));
        const float4 k0 = kv[0], k1 = kv[1], k2 = kv[2], k3 = kv[3];
        float p = q0.x * k0.x + q0.y * k0.y + q0.z * k0.z + q0.w * k0.w
                + q1.x * k1.x + q1.y * k1.y + q1.z * k1.z + q1.w * k1.w
                + q2.x * k2.x + q2.y * k2.y + q2.z * k2.z + q2.w * k2.w
                + q3.x * k3.x + q3.y * k3.y + q3.z * k3.z + q3.w * k3.w;
        p += __shfl_xor(p, 1);
        p += __shfl_xor(p, 2);
        // all 4 lanes of the d-group now hold the full dot for sample s
        mx = fmaxf(mx, p);
        sm += p;
    }
    // combine the 16 sample-slots (masks 4..32 only: d-group lanes are dups)
#pragma unroll
    for (int m = 4; m < 64; m <<= 1) {
        mx = fmaxf(mx, __shfl_xor(mx, m));
        sm += __shfl_xor(sm, m);
    }
    if (lane == 0) M[w] = mx - sm * (1.0f / (float)NL);
}

// ---------------------------------------------------------------------------
// Kernel 2: per (b,h), top-40 of 2048 M values (iterative argmax,
// lower index wins ties -- matches jax.lax.top_k selection set).
// ---------------------------------------------------------------------------
__global__ __launch_bounds__(256) void k_topk(
    const float* __restrict__ M, int* __restrict__ Mtop)
{
    __shared__ float sM[NL];
    __shared__ float rv[4];
    __shared__ int   ri[4];
    const int bh = blockIdx.x;
    const int t  = threadIdx.x;

    for (int j = t; j < NL; j += 256) sM[j] = M[bh * NL + j];
    __syncthreads();

    for (int it = 0; it < NUTOP; ++it) {
        float v = -INFINITY;
        int   i = NL;
        for (int j = t; j < NL; j += 256) {
            const float m = sM[j];
            if (m > v || (m == v && j < i)) { v = m; i = j; }
        }
#pragma unroll
        for (int off = 1; off < 64; off <<= 1) {
            const float ov = __shfl_xor(v, off);
            const int   oi = __shfl_xor(i, off);
            if (ov > v || (ov == v && oi < i)) { v = ov; i = oi; }
        }
        const int wid = t >> 6;
        if ((t & 63) == 0) { rv[wid] = v; ri[wid] = i; }
        __syncthreads();
        if (t == 0) {
            for (int w2 = 1; w2 < 4; ++w2) {
                if (rv[w2] > v || (rv[w2] == v && ri[w2] < i)) { v = rv[w2]; i = ri[w2]; }
            }
            Mtop[bh * NUTOP + it] = i;
            sM[i] = -INFINITY;
        }
        __syncthreads();
    }
}

// ---------------------------------------------------------------------------
// Kernel 3: for each selected row: scores = (q_row . K^T)/8, softmax,
// write the 2048-wide attn row into the (zeroed) dense output.
// One block (256 thr) per (b,h,u); each thread owns 8 columns.
// ---------------------------------------------------------------------------
__global__ __launch_bounds__(256) void k_attn(
    const float* __restrict__ q, const float* __restrict__ k,
    const int* __restrict__ Mtop, float* __restrict__ out)
{
    __shared__ float redm[4];
    __shared__ float reds[4];

    const int bh  = blockIdx.x / NUTOP;
    const int ui  = blockIdx.x % NUTOP;
    const int b   = bh >> 3;
    const int h   = bh & 7;
    const int row = Mtop[bh * NUTOP + ui];
    const int t   = threadIdx.x;
    const int lane = t & 63;
    const int wid  = t >> 6;

    // q row is wave-uniform: broadcast loads, kept in registers
    const float4* qv = (const float4*)(q + (((size_t)(b * NL + row)) * NH + h) * ND);
    float4 qr[16];
#pragma unroll
    for (int i = 0; i < 16; ++i) qr[i] = qv[i];

    float sc[8];
    float mx = -INFINITY;
#pragma unroll
    for (int j = 0; j < 8; ++j) {
        const int l = t + 256 * j;
        const float4* kv = (const float4*)(k + (((size_t)(b * NL + l)) * NH + h) * ND);
        float s = 0.0f;
#pragma unroll
        for (int i = 0; i < 16; ++i) {
            const float4 kk = kv[i];
            s += qr[i].x * kk.x + qr[i].y * kk.y + qr[i].z * kk.z + qr[i].w * kk.w;
        }
        sc[j] = s * 0.125f;   // 1/sqrt(64)
        mx = fmaxf(mx, sc[j]);
    }

    // block max
#pragma unroll
    for (int off = 1; off < 64; off <<= 1) mx = fmaxf(mx, __shfl_xor(mx, off));
    if (lane == 0) redm[wid] = mx;
    __syncthreads();
    mx = fmaxf(fmaxf(redm[0], redm[1]), fmaxf(redm[2], redm[3]));

    float lsum = 0.0f;
#pragma unroll
    for (int j = 0; j < 8; ++j) {
        sc[j] = __expf(sc[j] - mx);
        lsum += sc[j];
    }
#pragma unroll
    for (int off = 1; off < 64; off <<= 1) lsum += __shfl_xor(lsum, off);
    if (lane == 0) reds[wid] = lsum;
    __syncthreads();
    const float inv = 1.0f / (reds[0] + reds[1] + reds[2] + reds[3]);

    float* orow = out + ((size_t)bh * NL + row) * NL;
#pragma unroll
    for (int j = 0; j < 8; ++j) {
        orow[t + 256 * j] = sc[j] * inv;
    }
}

extern "C" void kernel_launch(void* const* d_in, const int* in_sizes, int n_in,
                              void* d_out, int out_size, void* d_ws, size_t ws_size,
                              hipStream_t stream) {
    const float* q   = (const float*)d_in[0];
    const float* k   = (const float*)d_in[1];
    const int*   idx = (const int*)d_in[2];
    float* out = (float*)d_out;

    float* Mws  = (float*)d_ws;                                   // B*H*L floats
    int*   Mtop = (int*)((char*)d_ws + (size_t)NB * NH * NL * 4); // B*H*40 ints

    // fused: compute M and zero the 512 MiB output (no hipMemsetAsync --
    // the rocclr fill kernel only reaches 1.7 TB/s)
    k_compute_M_zero<<<NB * NH * NL / 4, 256, 0, stream>>>(q, k, idx, Mws, (float4*)out);
    k_topk<<<NB * NH, 256, 0, stream>>>(Mws, Mtop);
    k_attn<<<NB * NH * NUTOP, 256, 0, stream>>>(q, k, Mtop, out);
}